// Round 5
// baseline (166.134 us; speedup 1.0000x reference)
//
#include <hip/hip_runtime.h>
#include <hip/hip_bf16.h>
#include <math.h>

#define NROWS 131072
#define NCODE 512
#define DIM 128
#define ROWS_B 128
#define MARGIN 2e-5f

typedef __attribute__((ext_vector_type(8))) short short8v;
typedef __attribute__((ext_vector_type(16))) float f32x16;

__device__ inline short f2bf(float v) {
    __hip_bfloat16 h = __float2bfloat16(v);
    return *reinterpret_cast<short*>(&h);
}
__device__ inline float bf2f(short s) {
    __hip_bfloat16 h;
    *reinterpret_cast<short*>(&h) = s;
    return __bfloat162float(h);
}

// ||e||^2 per code (fp32)
__global__ void e2_kernel(const float* __restrict__ emb, float* __restrict__ e2) {
    int c = blockIdx.x * blockDim.x + threadIdx.x;
    if (c < NCODE) {
        const float* e = emb + (size_t)c * DIM;
        float s = 0.f;
        #pragma unroll
        for (int l = 0; l < DIM; ++l) s = fmaf(e[l], e[l], s);
        e2[c] = s;
    }
}

// Pack emb into MFMA A-fragment lane order, bf16 hi/lo:
//   ahp[((mt*8)+kk)*64 + lane] = bf16hi(emb[code = mt*32 + (lane&31)][kk*16 + (lane>>5)*8 .. +8])
__global__ __launch_bounds__(256) void prep_pack(const float* __restrict__ emb,
        short8v* __restrict__ ahp, short8v* __restrict__ alp) {
    int gid = blockIdx.x * 256 + threadIdx.x;       // 32 blocks x 256 = 8192
    int lane = gid & 63, kk = (gid >> 6) & 7, c32 = gid >> 9;
    int code = c32 * 32 + (lane & 31);
    int d0 = kk * 16 + (lane >> 5) * 8;
    const float* src = emb + (size_t)code * DIM + d0;
    float4 v0 = *reinterpret_cast<const float4*>(src);
    float4 v1 = *reinterpret_cast<const float4*>(src + 4);
    float f[8] = {v0.x, v0.y, v0.z, v0.w, v1.x, v1.y, v1.z, v1.w};
    short8v h, l;
    #pragma unroll
    for (int j = 0; j < 8; ++j) {
        short hj = f2bf(f[j]);
        h[j] = hj;
        l[j] = f2bf(f[j] - bf2f(hj));
    }
    ahp[gid] = h;
    alp[gid] = l;
}

#define MFMA3(ACC, AH, AL, BH, BL)                                         \
    ACC = __builtin_amdgcn_mfma_f32_32x32x16_bf16(AH, BH, ACC, 0, 0, 0);   \
    ACC = __builtin_amdgcn_mfma_f32_32x32x16_bf16(AH, BL, ACC, 0, 0, 0);   \
    ACC = __builtin_amdgcn_mfma_f32_32x32x16_bf16(AL, BH, ACC, 0, 0, 0);

// D[m=code][n=row]; code = CB + (r&3) + 8*(r>>2) + 4*g, row = NT*32 + (lane&31).
#define PROC(ACC, CB, NT)                                                  \
    _Pragma("unroll")                                                      \
    for (int r = 0; r < 16; ++r) {                                         \
        int code = (CB) + (r & 3) + 8 * (r >> 2) + 4 * g;                  \
        float sv = e2s[code] - 2.0f * (ACC)[r];                            \
        bool lt = sv < m1_##NT;                                            \
        m2_##NT = lt ? m1_##NT : fminf(m2_##NT, sv);                       \
        if (lt) { m1_##NT = sv; i1_##NT = code; }                          \
    }

#define XMERGE(NT) {                                                       \
    float pm1 = __shfl_xor(m1_##NT, 32);                                   \
    float pm2 = __shfl_xor(m2_##NT, 32);                                   \
    int   pi  = __shfl_xor(i1_##NT, 32);                                   \
    bool pb = (pm1 < m1_##NT) || (pm1 == m1_##NT && pi < i1_##NT);         \
    float loser = pb ? m1_##NT : pm1;                                      \
    m2_##NT = fminf(fminf(m2_##NT, pm2), loser);                           \
    if (pb) { m1_##NT = pm1; i1_##NT = pi; }                               \
}

__global__ __launch_bounds__(256, 2) void vq_main(
        const float* __restrict__ x, const float* __restrict__ emb,
        const short8v* __restrict__ ahp, const short8v* __restrict__ alp,
        const float* __restrict__ e2g, unsigned int* __restrict__ hist,
        float* __restrict__ out0, float* __restrict__ out1, float* __restrict__ out2) {
    __shared__ short xs_hi[ROWS_B][DIM];   // XOR-swizzled: short index d ^ ((row&15)<<3)
    __shared__ short xs_lo[ROWS_B][DIM];
    __shared__ float e2s[NCODE];
    __shared__ float x2s[ROWS_B];
    __shared__ float wm1[4][ROWS_B], wm2[4][ROWS_B];
    __shared__ int   wi1[4][ROWS_B];
    __shared__ int   s_idx[ROWS_B];
    __shared__ float s_fin[ROWS_B];
    __shared__ int   s_need[ROWS_B];

    const int tid = threadIdx.x;
    const long row0 = (long)blockIdx.x * ROWS_B;

    // ---- stage x -> bf16 hi/lo in LDS (swizzled), coalesced float4 ----
    const float4* xg = reinterpret_cast<const float4*>(x + row0 * DIM);
    #pragma unroll
    for (int it = 0; it < 16; ++it) {
        int i = tid + it * 256;
        int r = i >> 5, d0 = (i & 31) * 4;
        float4 v = xg[i];
        short4 h, l;
        h.x = f2bf(v.x); h.y = f2bf(v.y); h.z = f2bf(v.z); h.w = f2bf(v.w);
        l.x = f2bf(v.x - bf2f(h.x));
        l.y = f2bf(v.y - bf2f(h.y));
        l.z = f2bf(v.z - bf2f(h.z));
        l.w = f2bf(v.w - bf2f(h.w));
        int dd = d0 ^ ((r & 15) << 3);
        *reinterpret_cast<short4*>(&xs_hi[r][dd]) = h;
        *reinterpret_cast<short4*>(&xs_lo[r][dd]) = l;
    }
    for (int i = tid; i < NCODE; i += 256) e2s[i] = e2g[i];
    // ---- x2 per row (fp32; L1/L2-hot re-read): 2 threads per row ----
    {
        int r = tid >> 1, q = tid & 1;
        const float4* xr = reinterpret_cast<const float4*>(x + (row0 + r) * DIM + q * 64);
        float s = 0.f;
        #pragma unroll
        for (int jj = 0; jj < 16; ++jj) {
            float4 v = xr[jj];
            s = fmaf(v.x, v.x, s); s = fmaf(v.y, v.y, s);
            s = fmaf(v.z, v.z, s); s = fmaf(v.w, v.w, s);
        }
        s += __shfl_down(s, 1, 64);
        if (q == 0) x2s[r] = s;
    }
    __syncthreads();

    const int wv = tid >> 6, lane = tid & 63;
    const int l31 = lane & 31, g = lane >> 5;
    const int bsw = (l31 & 15) << 3;

    float m1_0 = 1e30f, m2_0 = 1e30f; int i1_0 = 0;
    float m1_1 = 1e30f, m2_1 = 1e30f; int i1_1 = 0;
    float m1_2 = 1e30f, m2_2 = 1e30f; int i1_2 = 0;
    float m1_3 = 1e30f, m2_3 = 1e30f; int i1_3 = 0;

    // ---- wave wv owns codes [wv*128, wv*128+128): 4 M-tiles, all 128 rows ----
    #pragma unroll 1
    for (int cc = 0; cc < 4; ++cc) {
        const int mt = wv * 4 + cc;
        f32x16 a0 = {}, a1 = {}, a2 = {}, a3 = {};

        #pragma unroll 2
        for (int kk = 0; kk < 8; ++kk) {
            short8v ah = ahp[(mt * 8 + kk) * 64 + lane];
            short8v al = alp[(mt * 8 + kk) * 64 + lane];

            const int dd = (kk * 16 + g * 8) ^ bsw;
            short8v bh0 = *reinterpret_cast<const short8v*>(&xs_hi[l31][dd]);
            short8v bh1 = *reinterpret_cast<const short8v*>(&xs_hi[32 + l31][dd]);
            short8v bh2 = *reinterpret_cast<const short8v*>(&xs_hi[64 + l31][dd]);
            short8v bh3 = *reinterpret_cast<const short8v*>(&xs_hi[96 + l31][dd]);
            short8v bl0 = *reinterpret_cast<const short8v*>(&xs_lo[l31][dd]);
            short8v bl1 = *reinterpret_cast<const short8v*>(&xs_lo[32 + l31][dd]);
            short8v bl2 = *reinterpret_cast<const short8v*>(&xs_lo[64 + l31][dd]);
            short8v bl3 = *reinterpret_cast<const short8v*>(&xs_lo[96 + l31][dd]);

            MFMA3(a0, ah, al, bh0, bl0);
            MFMA3(a1, ah, al, bh1, bl1);
            MFMA3(a2, ah, al, bh2, bl2);
            MFMA3(a3, ah, al, bh3, bl3);
        }
        const int cb = mt * 32;
        PROC(a0, cb, 0)
        PROC(a1, cb, 1)
        PROC(a2, cb, 2)
        PROC(a3, cb, 3)
    }

    // merge complementary code-halves (lane r <-> r+32, same row)
    XMERGE(0)
    XMERGE(1)
    XMERGE(2)
    XMERGE(3)
    if (lane < 32) {
        wm1[wv][l31]      = m1_0; wm2[wv][l31]      = m2_0; wi1[wv][l31]      = i1_0;
        wm1[wv][32 + l31] = m1_1; wm2[wv][32 + l31] = m2_1; wi1[wv][32 + l31] = i1_1;
        wm1[wv][64 + l31] = m1_2; wm2[wv][64 + l31] = m2_2; wi1[wv][64 + l31] = i1_2;
        wm1[wv][96 + l31] = m1_3; wm2[wv][96 + l31] = m2_3; wi1[wv][96 + l31] = i1_3;
    }
    __syncthreads();

    // ---- cross-wave merge (4 code-groups), margin test ----
    if (tid < ROWS_B) {
        float m1 = wm1[0][tid], m2 = wm2[0][tid]; int i1 = wi1[0][tid];
        #pragma unroll
        for (int w = 1; w < 4; ++w) {
            float pm1 = wm1[w][tid], pm2 = wm2[w][tid]; int pi = wi1[w][tid];
            bool pb = (pm1 < m1) || (pm1 == m1 && pi < i1);
            float loser = pb ? m1 : pm1;
            m2 = fminf(fminf(m2, pm2), loser);
            if (pb) { m1 = pm1; i1 = pi; }
        }
        s_idx[tid] = i1; s_fin[tid] = m1;
        s_need[tid] = (m2 - m1 < MARGIN) ? 1 : 0;
    }
    __syncthreads();

    // ---- fp64 rescue for near-tie rows (exact argmin, lowest-index ties) ----
    for (int row = wv; row < ROWS_B; row += 4) {
        if (!s_need[row]) continue;            // wave-uniform
        const float4* xr = reinterpret_cast<const float4*>(x + (row0 + row) * DIM);
        double best = 1e300; int bi = NCODE;
        for (int q = 0; q < 8; ++q) {
            int code = q * 64 + lane;
            const float4* er = reinterpret_cast<const float4*>(emb + (size_t)code * DIM);
            double s = 0.0;
            for (int j = 0; j < 32; ++j) {
                float4 xv = xr[j];
                float4 ev = er[j];
                double d0 = (double)xv.x - (double)ev.x;
                double d1 = (double)xv.y - (double)ev.y;
                double d2 = (double)xv.z - (double)ev.z;
                double d3 = (double)xv.w - (double)ev.w;
                s = fma(d0, d0, s); s = fma(d1, d1, s);
                s = fma(d2, d2, s); s = fma(d3, d3, s);
            }
            if (s < best) { best = s; bi = code; }   // ascending q -> lowest index kept
        }
        for (int off = 1; off < 64; off <<= 1) {
            double ob = __shfl_xor(best, off);
            int    oi = __shfl_xor(bi, off);
            if (ob < best || (ob == best && oi < bi)) { best = ob; bi = oi; }
        }
        if (lane == 0) {
            s_idx[row] = bi;
            s_fin[row] = (float)best - x2s[row];
        }
    }
    __syncthreads();

    // ---- out0: gather selected codebook rows (exact fp32) ----
    float4* o0 = reinterpret_cast<float4*>(out0 + row0 * DIM);
    #pragma unroll
    for (int it = 0; it < 16; ++it) {
        int i = tid + it * 256;
        int r = i >> 5, j = i & 31;
        int code = s_idx[r];
        o0[i] = reinterpret_cast<const float4*>(emb + (size_t)code * DIM)[j];
    }
    // ---- out1/out2 + histogram ----
    if (tid < ROWS_B) {
        float o = x2s[tid] + s_fin[tid];
        out1[row0 + tid] = o;
        out2[row0 + tid] = o;
        atomicAdd(&hist[s_idx[tid]], 1u);
    }
}

__global__ void entropy_kernel(const unsigned int* __restrict__ hist, float* __restrict__ oent) {
    __shared__ float red[8];
    int tid = threadIdx.x;  // 512 threads
    float p = (float)hist[tid] * (1.0f / 131072.0f);
    float t = (p > 0.f) ? (-p * logf(p)) : 0.f;
    #pragma unroll
    for (int off = 32; off > 0; off >>= 1) t += __shfl_down(t, off);
    if ((tid & 63) == 0) red[tid >> 6] = t;
    __syncthreads();
    if (tid == 0) {
        float s = 0.f;
        #pragma unroll
        for (int i = 0; i < 8; ++i) s += red[i];
        *oent = s;
    }
}

extern "C" void kernel_launch(void* const* d_in, const int* in_sizes, int n_in,
                              void* d_out, int out_size, void* d_ws, size_t ws_size,
                              hipStream_t stream) {
    const float* x   = (const float*)d_in[0];
    const float* emb = (const float*)d_in[1];
    float* out  = (float*)d_out;
    float* out0 = out;
    float* out1 = out0 + (size_t)NROWS * DIM;
    float* out2 = out1 + NROWS;
    float* oent = out2 + NROWS;

    unsigned int* hist = (unsigned int*)d_ws;
    float* e2g = (float*)((char*)d_ws + 4096);
    short8v* ahp = (short8v*)((char*)d_ws + 8192);
    short8v* alp = (short8v*)((char*)d_ws + 8192 + NCODE * DIM * 2);

    hipMemsetAsync(d_ws, 0, 4096, stream);   // zero histogram (ws is poisoned, not re-zeroed)
    e2_kernel<<<2, 256, 0, stream>>>(emb, e2g);
    prep_pack<<<32, 256, 0, stream>>>(emb, ahp, alp);
    vq_main<<<NROWS / ROWS_B, 256, 0, stream>>>(x, emb, ahp, alp, e2g, hist, out0, out1, out2);
    entropy_kernel<<<1, NCODE, 0, stream>>>(hist, oent);
}

// Round 6
// 133.153 us; speedup vs baseline: 1.2477x; 1.2477x over previous
//
#include <hip/hip_runtime.h>
#include <hip/hip_bf16.h>
#include <math.h>

#define NROWS 131072
#define NCODE 512
#define DIM 128
#define ROWS_B 64
#define MARGIN 2e-6f   // score err <= ~2e-7 (bf16 hi/lo products exact in fp32); 10x safety

typedef __attribute__((ext_vector_type(8))) short short8v;
typedef __attribute__((ext_vector_type(16))) float f32x16;

__device__ inline short f2bf(float v) {
    __hip_bfloat16 h = __float2bfloat16(v);
    return *reinterpret_cast<short*>(&h);
}
__device__ inline float bf2f(short s) {
    __hip_bfloat16 h;
    *reinterpret_cast<short*>(&h) = s;
    return __bfloat162float(h);
}

// ||e||^2 per code (fp32)
__global__ void e2_kernel(const float* __restrict__ emb, float* __restrict__ e2) {
    int c = blockIdx.x * blockDim.x + threadIdx.x;
    if (c < NCODE) {
        const float* e = emb + (size_t)c * DIM;
        float s = 0.f;
        #pragma unroll
        for (int l = 0; l < DIM; ++l) s = fmaf(e[l], e[l], s);
        e2[c] = s;
    }
}

// Pack emb into MFMA A-fragment lane order, bf16 hi/lo:
//   ahp[((c32*8)+kk)*64 + lane] = bf16hi(emb[code = c32*32 + (lane&31)][kk*16 + (lane>>5)*8 .. +8])
// so vq_main's A-loads are fully coalesced (64 lanes x 16B contiguous).
__global__ __launch_bounds__(256) void prep_pack(const float* __restrict__ emb,
        short8v* __restrict__ ahp, short8v* __restrict__ alp) {
    int gid = blockIdx.x * 256 + threadIdx.x;       // 32 blocks x 256 = 8192
    int lane = gid & 63, kk = (gid >> 6) & 7, c32 = gid >> 9;
    int code = c32 * 32 + (lane & 31);
    int d0 = kk * 16 + (lane >> 5) * 8;
    const float* src = emb + (size_t)code * DIM + d0;
    float4 v0 = *reinterpret_cast<const float4*>(src);
    float4 v1 = *reinterpret_cast<const float4*>(src + 4);
    float f[8] = {v0.x, v0.y, v0.z, v0.w, v1.x, v1.y, v1.z, v1.w};
    short8v h, l;
    #pragma unroll
    for (int j = 0; j < 8; ++j) {
        short hj = f2bf(f[j]);
        h[j] = hj;
        l[j] = f2bf(f[j] - bf2f(hj));
    }
    ahp[gid] = h;
    alp[gid] = l;
}

#define MFMA3(ACC, AH, AL, BH, BL)                                         \
    ACC = __builtin_amdgcn_mfma_f32_32x32x16_bf16(AH, BH, ACC, 0, 0, 0);   \
    ACC = __builtin_amdgcn_mfma_f32_32x32x16_bf16(AH, BL, ACC, 0, 0, 0);   \
    ACC = __builtin_amdgcn_mfma_f32_32x32x16_bf16(AL, BH, ACC, 0, 0, 0);

// D[m=code][n=row]; code = CB + (r&3) + 8*(r>>2) + 4*g, row(col) = lane&31.
#define PROC(ACC, CB, NT)                                                  \
    _Pragma("unroll")                                                      \
    for (int r = 0; r < 16; ++r) {                                         \
        int code = (CB) + (r & 3) + 8 * (r >> 2) + 4 * g;                  \
        float sv = e2s[code] - 2.0f * (ACC)[r];                            \
        bool lt = sv < m1_##NT;                                            \
        m2_##NT = lt ? m1_##NT : fminf(m2_##NT, sv);                       \
        if (lt) { m1_##NT = sv; i1_##NT = code; }                          \
    }

#define XMERGE(NT) {                                                       \
    float pm1 = __shfl_xor(m1_##NT, 32);                                   \
    float pm2 = __shfl_xor(m2_##NT, 32);                                   \
    int   pi  = __shfl_xor(i1_##NT, 32);                                   \
    bool pb = (pm1 < m1_##NT) || (pm1 == m1_##NT && pi < i1_##NT);         \
    float loser = pb ? m1_##NT : pm1;                                      \
    m2_##NT = fminf(fminf(m2_##NT, pm2), loser);                           \
    if (pb) { m1_##NT = pm1; i1_##NT = pi; }                               \
}

__global__ __launch_bounds__(256, 3) void vq_main(
        const float* __restrict__ x, const float* __restrict__ emb,
        const short8v* __restrict__ ahp, const short8v* __restrict__ alp,
        const float* __restrict__ e2g, unsigned int* __restrict__ hist,
        float* __restrict__ out0, float* __restrict__ out1, float* __restrict__ out2) {
    __shared__ short xs_hi[ROWS_B][DIM];   // XOR-swizzled: short index d ^ ((row&15)<<3)
    __shared__ short xs_lo[ROWS_B][DIM];
    __shared__ float e2s[NCODE];
    __shared__ float x2s[ROWS_B];
    __shared__ float wm1[4][ROWS_B], wm2[4][ROWS_B];
    __shared__ int   wi1[4][ROWS_B];
    __shared__ int   s_idx[ROWS_B];
    __shared__ float s_fin[ROWS_B];
    __shared__ int   s_need[ROWS_B];

    const int tid = threadIdx.x;
    const long row0 = (long)blockIdx.x * ROWS_B;

    // ---- stage x -> bf16 hi/lo in LDS (swizzled), coalesced float4 ----
    const float4* xg = reinterpret_cast<const float4*>(x + row0 * DIM);
    #pragma unroll
    for (int it = 0; it < 8; ++it) {
        int i = tid + it * 256;
        int r = i >> 5, d0 = (i & 31) * 4;
        float4 v = xg[i];
        short4 h, l;
        h.x = f2bf(v.x); h.y = f2bf(v.y); h.z = f2bf(v.z); h.w = f2bf(v.w);
        l.x = f2bf(v.x - bf2f(h.x));
        l.y = f2bf(v.y - bf2f(h.y));
        l.z = f2bf(v.z - bf2f(h.z));
        l.w = f2bf(v.w - bf2f(h.w));
        int dd = d0 ^ ((r & 15) << 3);
        *reinterpret_cast<short4*>(&xs_hi[r][dd]) = h;
        *reinterpret_cast<short4*>(&xs_lo[r][dd]) = l;
    }
    for (int i = tid; i < NCODE; i += 256) e2s[i] = e2g[i];
    // ---- x2 per row (fp32; L1/L2-hot re-read) ----
    {
        int r = tid >> 2, q = tid & 3;
        const float4* xr = reinterpret_cast<const float4*>(x + (row0 + r) * DIM + q * 32);
        float s = 0.f;
        #pragma unroll
        for (int jj = 0; jj < 8; ++jj) {
            float4 v = xr[jj];
            s = fmaf(v.x, v.x, s); s = fmaf(v.y, v.y, s);
            s = fmaf(v.z, v.z, s); s = fmaf(v.w, v.w, s);
        }
        s += __shfl_down(s, 1, 64);
        s += __shfl_down(s, 2, 64);
        if (q == 0) x2s[r] = s;
    }
    __syncthreads();

    const int wv = tid >> 6, lane = tid & 63;
    const int l31 = lane & 31, g = lane >> 5;
    const int bsw = (l31 & 15) << 3;

    float m1_0 = 1e30f, m2_0 = 1e30f; int i1_0 = 0;
    float m1_1 = 1e30f, m2_1 = 1e30f; int i1_1 = 0;

    // ---- two 256-code passes; wave covers codes cc*256 + wv*64 .. +64 ----
    #pragma unroll 1
    for (int cc = 0; cc < 2; ++cc) {
        const int t0 = cc * 8 + wv * 2;            // two 32-code tiles t0, t0+1
        f32x16 a00 = {}, a10 = {}, a01 = {}, a11 = {};

        #pragma unroll 2
        for (int kk = 0; kk < 8; ++kk) {
            short8v ah0 = ahp[(t0 * 8 + kk) * 64 + lane];
            short8v ah1 = ahp[((t0 + 1) * 8 + kk) * 64 + lane];
            short8v al0 = alp[(t0 * 8 + kk) * 64 + lane];
            short8v al1 = alp[((t0 + 1) * 8 + kk) * 64 + lane];

            const int dd = (kk * 16 + g * 8) ^ bsw;
            short8v bh0 = *reinterpret_cast<const short8v*>(&xs_hi[l31][dd]);
            short8v bh1 = *reinterpret_cast<const short8v*>(&xs_hi[32 + l31][dd]);
            short8v bl0 = *reinterpret_cast<const short8v*>(&xs_lo[l31][dd]);
            short8v bl1 = *reinterpret_cast<const short8v*>(&xs_lo[32 + l31][dd]);

            MFMA3(a00, ah0, al0, bh0, bl0);
            MFMA3(a10, ah1, al1, bh0, bl0);
            MFMA3(a01, ah0, al0, bh1, bl1);
            MFMA3(a11, ah1, al1, bh1, bl1);
        }
        const int cb = cc * 256 + wv * 64;
        PROC(a00, cb,      0)
        PROC(a10, cb + 32, 0)
        PROC(a01, cb,      1)
        PROC(a11, cb + 32, 1)
    }

    // merge complementary code-halves (lane r <-> r+32, same row)
    XMERGE(0)
    XMERGE(1)
    if (lane < 32) {
        wm1[wv][l31] = m1_0; wm2[wv][l31] = m2_0; wi1[wv][l31] = i1_0;
        wm1[wv][32 + l31] = m1_1; wm2[wv][32 + l31] = m2_1; wi1[wv][32 + l31] = i1_1;
    }
    __syncthreads();

    // ---- cross-wave merge (4 code-groups), margin test ----
    if (tid < ROWS_B) {
        float m1 = wm1[0][tid], m2 = wm2[0][tid]; int i1 = wi1[0][tid];
        #pragma unroll
        for (int w = 1; w < 4; ++w) {
            float pm1 = wm1[w][tid], pm2 = wm2[w][tid]; int pi = wi1[w][tid];
            bool pb = (pm1 < m1) || (pm1 == m1 && pi < i1);
            float loser = pb ? m1 : pm1;
            m2 = fminf(fminf(m2, pm2), loser);
            if (pb) { m1 = pm1; i1 = pi; }
        }
        s_idx[tid] = i1; s_fin[tid] = m1;
        s_need[tid] = (m2 - m1 < MARGIN) ? 1 : 0;
    }
    __syncthreads();

    // ---- fp64 rescue for near-tie rows (exact argmin, lowest-index ties) ----
    for (int row = wv; row < ROWS_B; row += 4) {
        if (!s_need[row]) continue;            // wave-uniform
        const float4* xr = reinterpret_cast<const float4*>(x + (row0 + row) * DIM);
        double best = 1e300; int bi = NCODE;
        for (int q = 0; q < 8; ++q) {
            int code = q * 64 + lane;
            const float4* er = reinterpret_cast<const float4*>(emb + (size_t)code * DIM);
            double s = 0.0;
            for (int j = 0; j < 32; ++j) {
                float4 xv = xr[j];
                float4 ev = er[j];
                double d0 = (double)xv.x - (double)ev.x;
                double d1 = (double)xv.y - (double)ev.y;
                double d2 = (double)xv.z - (double)ev.z;
                double d3 = (double)xv.w - (double)ev.w;
                s = fma(d0, d0, s); s = fma(d1, d1, s);
                s = fma(d2, d2, s); s = fma(d3, d3, s);
            }
            if (s < best) { best = s; bi = code; }   // ascending q -> lowest index kept
        }
        for (int off = 1; off < 64; off <<= 1) {
            double ob = __shfl_xor(best, off);
            int    oi = __shfl_xor(bi, off);
            if (ob < best || (ob == best && oi < bi)) { best = ob; bi = oi; }
        }
        if (lane == 0) {
            s_idx[row] = bi;
            s_fin[row] = (float)best - x2s[row];
        }
    }
    __syncthreads();

    // ---- out0: gather selected codebook rows (exact fp32) ----
    float4* o0 = reinterpret_cast<float4*>(out0 + row0 * DIM);
    #pragma unroll
    for (int it = 0; it < 8; ++it) {
        int i = tid + it * 256;
        int r = i >> 5, j = i & 31;
        int code = s_idx[r];
        o0[i] = reinterpret_cast<const float4*>(emb + (size_t)code * DIM)[j];
    }
    // ---- out1/out2 + histogram ----
    if (tid < ROWS_B) {
        float o = x2s[tid] + s_fin[tid];
        out1[row0 + tid] = o;
        out2[row0 + tid] = o;
        atomicAdd(&hist[s_idx[tid]], 1u);
    }
}

__global__ void entropy_kernel(const unsigned int* __restrict__ hist, float* __restrict__ oent) {
    __shared__ float red[8];
    int tid = threadIdx.x;  // 512 threads
    float p = (float)hist[tid] * (1.0f / 131072.0f);
    float t = (p > 0.f) ? (-p * logf(p)) : 0.f;
    #pragma unroll
    for (int off = 32; off > 0; off >>= 1) t += __shfl_down(t, off);
    if ((tid & 63) == 0) red[tid >> 6] = t;
    __syncthreads();
    if (tid == 0) {
        float s = 0.f;
        #pragma unroll
        for (int i = 0; i < 8; ++i) s += red[i];
        *oent = s;
    }
}

extern "C" void kernel_launch(void* const* d_in, const int* in_sizes, int n_in,
                              void* d_out, int out_size, void* d_ws, size_t ws_size,
                              hipStream_t stream) {
    const float* x   = (const float*)d_in[0];
    const float* emb = (const float*)d_in[1];
    float* out  = (float*)d_out;
    float* out0 = out;
    float* out1 = out0 + (size_t)NROWS * DIM;
    float* out2 = out1 + NROWS;
    float* oent = out2 + NROWS;

    unsigned int* hist = (unsigned int*)d_ws;
    float* e2g = (float*)((char*)d_ws + 4096);
    short8v* ahp = (short8v*)((char*)d_ws + 8192);
    short8v* alp = (short8v*)((char*)d_ws + 8192 + NCODE * DIM * 2);

    hipMemsetAsync(d_ws, 0, 4096, stream);   // zero histogram (ws is poisoned, not re-zeroed)
    e2_kernel<<<2, 256, 0, stream>>>(emb, e2g);
    prep_pack<<<32, 256, 0, stream>>>(emb, ahp, alp);
    vq_main<<<NROWS / ROWS_B, 256, 0, stream>>>(x, emb, ahp, alp, e2g, hist, out0, out1, out2);
    entropy_kernel<<<1, NCODE, 0, stream>>>(hist, oent);
}